// Round 3
// baseline (365.933 us; speedup 1.0000x reference)
//
#include <hip/hip_runtime.h>
#include <hip/hip_bf16.h>

// Problem geometry (fixed by setup_inputs):
//   x: (N=64, C=256, H=56, W=56) f32; NS=8, NB=8, FOLDS=64, GROUPS=2, FI=16
//   HW = 3136 floats = 784 float4 per (n,c) plane
//   out = x_out (64*256*3136) ++ x_offset (16) ++ x_weight (128)

#define HW4      784          // 3136/4
#define N_TOT    64
#define C_TOT    256
#define FOLDS    64
#define MAIN_OUT (64u*256u*784u)   // float4 count = 12,845,056
#define OFF_OUT  51380224          // float offset of x_offset in d_out
#define WT_OUT   51380240          // float offset of x_weight in d_out

// Native clang vector — required for __builtin_nontemporal_* (HIP's float4
// is a class type the builtin rejects).
typedef float v4f __attribute__((ext_vector_type(4)));

// ---------------- K1: mean-pool first 64 channels over 56x56 ----------------
__global__ __launch_bounds__(256) void pool_kernel(const v4f* __restrict__ x,
                                                   float* __restrict__ pool) {
    const int p = blockIdx.x;          // 0..4095 : p = n*64 + f
    const int n = p >> 6, f = p & 63;
    const v4f* base = x + (size_t)(n * C_TOT + f) * HW4;
    float s = 0.f;
    for (int i = threadIdx.x; i < HW4; i += 256) {
        v4f v = base[i];
        s += (v.x + v.y) + (v.z + v.w);
    }
    for (int m = 32; m >= 1; m >>= 1) s += __shfl_xor(s, m, 64);
    __shared__ float ls[4];
    if ((threadIdx.x & 63) == 0) ls[threadIdx.x >> 6] = s;
    __syncthreads();
    if (threadIdx.x == 0)
        pool[p] = (ls[0] + ls[1] + ls[2] + ls[3]) * (1.0f / 3136.0f);
}

// ---------------- K2: tiny offset/weight math + param table ----------------
__global__ __launch_bounds__(256) void mid_kernel(const float* __restrict__ pool,
    const float* __restrict__ cow, const float* __restrict__ cob,
    const float* __restrict__ f1w, const float* __restrict__ f1b,
    const float* __restrict__ f2w, const float* __restrict__ f2b,
    const float* __restrict__ cww, const float* __restrict__ cwb,
    float* __restrict__ out_off, float* __restrict__ out_wt,
    v4f* __restrict__ param) {
    __shared__ float sp[4096];   // pooled[n][f], n = b*8+s
    __shared__ float sxo[64];    // conv-offset out [b][s]
    __shared__ float sxw[128];   // conv-weight out [b][g][s]
    __shared__ float sy[64];     // fc1 out [b][j]
    __shared__ float soff[16];   // x_offset [b][g] (already negated)
    __shared__ float swt[128];   // x_weight [b][s][g]
    const int t = threadIdx.x;
    for (int i = t; i < 4096; i += 256) sp[i] = pool[i];
    __syncthreads();
    if (t < 64) {                         // conv1d for offsets: (8,64,8) -> (8,8)
        const int b = t >> 3, s = t & 7;
        float acc = cob[0];
        for (int f = 0; f < 64; ++f) {
            float vm = (s >= 1) ? sp[(b*8 + s - 1)*64 + f] : 0.f;
            float v0 = sp[(b*8 + s)*64 + f];
            float vp = (s <= 6) ? sp[(b*8 + s + 1)*64 + f] : 0.f;
            acc += cow[f*3+0]*vm + cow[f*3+1]*v0 + cow[f*3+2]*vp;
        }
        sxo[t] = acc;
    } else if (t < 192) {                 // conv1d for weights: (8,64,8) -> (8,2,8)
        const int j = t - 64;
        const int b = j >> 4, g = (j >> 3) & 1, s = j & 7;
        float acc = cwb[g];
        for (int f = 0; f < 64; ++f) {
            float vm = (s >= 1) ? sp[(b*8 + s - 1)*64 + f] : 0.f;
            float v0 = sp[(b*8 + s)*64 + f];
            float vp = (s <= 6) ? sp[(b*8 + s + 1)*64 + f] : 0.f;
            const float* w = &cww[(g*64 + f)*3];
            acc += w[0]*vm + w[1]*v0 + w[2]*vp;
        }
        sxw[j] = acc;
    }
    __syncthreads();
    if (t < 64) {                         // fc1 + relu
        const int b = t >> 3, j = t & 7;
        float acc = f1b[j];
        for (int s = 0; s < 8; ++s) acc += sxo[b*8+s] * f1w[j*8+s];
        sy[t] = fmaxf(acc, 0.f);
    } else if (t < 192) {                 // x_weight = 2*sigmoid(xw)^T
        const int q = t - 64;
        const int b = q >> 4, s = (q >> 1) & 7, g = q & 1;
        float wv = 2.f / (1.f + expf(-sxw[b*16 + g*8 + s]));
        swt[b*16 + s*2 + g] = wv;
        out_wt[b*16 + s*2 + g] = wv;
    }
    __syncthreads();
    if (t < 16) {                         // fc2 + sigmoid -> negated offset
        const int b = t >> 1, g = t & 1;
        float acc = f2b[g];
        for (int j = 0; j < 8; ++j) acc += sy[b*8+j] * f2w[g*8+j];
        float off = -(4.f * (1.f / (1.f + expf(-acc)) - 0.5f));
        soff[b*2+g] = off;
        out_off[b*2+g] = off;
    }
    __syncthreads();
    {   // param table: one entry per (b, s, part) ; t = (b*8+s)*4 + part
        const int i = t & 3, s = (t >> 2) & 7, b = t >> 5;
        const int g = i & 1;
        float d = soff[b*2+g];
        if (i >= 2) d = -d;               // parts 2,3 use -x_offset
        float off = d + (float)(s + 1);
        int fi = (int)floorf(off);
        int o0 = min(max(fi, 0), 9);
        int o1 = min(max(fi + 1, 0), 9);
        float w0 = 1.f - (off - (float)o0);
        int n0 = (o0 >= 1 && o0 <= 8) ? (b*8 + o0 - 1) : -1;   // source row or pad
        int n1 = (o1 >= 1 && o1 <= 8) ? (b*8 + o1 - 1) : -1;
        float wt = swt[b*16 + s*2 + g];
        v4f pv;
        pv.x = __int_as_float(n0);
        pv.y = __int_as_float(n1);
        pv.z = w0;
        pv.w = wt;
        param[(b*8 + s)*4 + i] = pv;
    }
}

// ---------------- K3: main output pass (blend for c<64, copy for c>=64) ----
// Copy-path loads and ALL stores are non-temporal: the streaming 154 MB copy
// and the 205 MB output must not evict the 51 MB gather working set (channels
// 0..63) from L2/L3 — the gather taps re-read those planes up to 2x.
__global__ __launch_bounds__(256) void out_kernel(const v4f* __restrict__ x,
                                                  const v4f* __restrict__ param,
                                                  v4f* __restrict__ out) {
    const unsigned stride = gridDim.x * blockDim.x;
    for (unsigned idx = blockIdx.x * blockDim.x + threadIdx.x; idx < MAIN_OUT;
         idx += stride) {
        const unsigned plane = idx / 784u;       // n*256 + c
        const unsigned r     = idx - plane * 784u;
        const unsigned c     = plane & 255u;
        v4f v;
        if (c >= 64u) {
            v = __builtin_nontemporal_load(&x[idx]);   // unchanged channels
        } else {
            const unsigned n = plane >> 8;
            const v4f p = param[n*4u + (c >> 4)];      // wave-uniform
            const int n0 = __float_as_int(p.x);
            const int n1 = __float_as_int(p.y);
            const float w0 = p.z, wt = p.w, w1 = 1.f - w0;
            v4f a = (v4f)(0.f);
            v4f b = (v4f)(0.f);
            if (n0 >= 0) a = x[((unsigned)n0 * 256u + c) * 784u + r];
            if (n1 >= 0) b = x[((unsigned)n1 * 256u + c) * 784u + r];
            v = (w0*a + w1*b) * wt;
        }
        __builtin_nontemporal_store(v, &out[idx]);
    }
}

extern "C" void kernel_launch(void* const* d_in, const int* in_sizes, int n_in,
                              void* d_out, int out_size, void* d_ws, size_t ws_size,
                              hipStream_t stream) {
    const float* x   = (const float*)d_in[0];
    const float* cow = (const float*)d_in[1];
    const float* cob = (const float*)d_in[2];
    const float* f1w = (const float*)d_in[3];
    const float* f1b = (const float*)d_in[4];
    const float* f2w = (const float*)d_in[5];
    const float* f2b = (const float*)d_in[6];
    const float* cww = (const float*)d_in[7];
    const float* cwb = (const float*)d_in[8];
    float* out = (float*)d_out;

    float* pool  = (float*)d_ws;                                // 4096 floats
    v4f*   param = (v4f*)((char*)d_ws + 4096 * sizeof(float));  // 256 v4f

    pool_kernel<<<4096, 256, 0, stream>>>((const v4f*)x, pool);
    mid_kernel<<<1, 256, 0, stream>>>(pool, cow, cob, f1w, f1b, f2w, f2b,
                                      cww, cwb, out + OFF_OUT, out + WT_OUT, param);
    out_kernel<<<2048, 256, 0, stream>>>((const v4f*)x, param, (v4f*)out);
}